// Round 4
// baseline (514.889 us; speedup 1.0000x reference)
//
#include <hip/hip_runtime.h>
#include <math.h>

#define SLEN 8000
#define NBATCH 512
#define DDIM 256

// ---- fused conv+pointwise config ----
#define RAD 160
#define TAPS 321                 // truncated Gaussian: tail mass ~1e-7
#define CHUNK 2048
#define CBLK 256
#define TPO 8
#define HALO_L 176               // 16 extra left so v_s[i0-1] is computable
#define WIN 2400                 // 176 + 2048 + 160 + 16 slack

// output element offsets (flat concat in reference return order)
#define O0  0            // dv_out sliced  512*7700
#define O1  3942400      // dv_t           512*8000
#define O2  8038400      // dv2_t          512*8000
#define O3  12134400     // a              512
#define O4  12134912     // k*1000         512
#define O5  12135424     // epsilon        512
#define O6  12135936     // gamma          512
#define O7  12136448     // t_             512*8000
#define O8  16232448     // dv_l           512*8001
#define O9  20328960     // dv_r           512*8001
#define O10 24425472     // t_out          512*8000

// unaligned-capable 16B vector (dv_l/dv_r rows are 8001 floats -> 4B aligned)
typedef float f4u __attribute__((vector_size(16), aligned(4)));

struct WTable { float w[TAPS]; };   // by-value kernarg; index ONLY with constants

// ---------------- params: one wave per row, shfl butterfly reduction ---------
__global__ __launch_bounds__(64) void pc_params_kernel(
    const float* __restrict__ b,
    const float* __restrict__ kw, const float* __restrict__ kb,
    const float* __restrict__ aw, const float* __restrict__ ab,
    const float* __restrict__ ew, const float* __restrict__ eb,
    const float* __restrict__ gw, const float* __restrict__ gb,
    float* __restrict__ out3, float* __restrict__ out4,
    float* __restrict__ out5, float* __restrict__ out6,
    float* __restrict__ wsp)
{
    const int row = blockIdx.x;
    const int l = threadIdx.x;
    const float4 bb = *(const float4*)(b + (long)row * DDIM + 4 * l);
    const float4 k4 = *(const float4*)(kw + 4 * l);
    const float4 a4 = *(const float4*)(aw + 4 * l);
    const float4 e4 = *(const float4*)(ew + 4 * l);
    const float4 g4 = *(const float4*)(gw + 4 * l);
    float sk = bb.x * k4.x + bb.y * k4.y + bb.z * k4.z + bb.w * k4.w;
    float sa = bb.x * a4.x + bb.y * a4.y + bb.z * a4.z + bb.w * a4.w;
    float se = bb.x * e4.x + bb.y * e4.y + bb.z * e4.z + bb.w * e4.w;
    float sg = bb.x * g4.x + bb.y * g4.y + bb.z * g4.z + bb.w * g4.w;
#pragma unroll
    for (int m = 1; m < 64; m <<= 1) {
        sk += __shfl_xor(sk, m, 64);
        sa += __shfl_xor(sa, m, 64);
        se += __shfl_xor(se, m, 64);
        sg += __shfl_xor(sg, m, 64);
    }
    if (l == 0) {
        float k = fminf(fmaxf(fmaxf(sk + kb[0], 0.0f), 0.1f),   1.0f);
        float a = fminf(fmaxf(fmaxf(sa + ab[0], 0.0f), 0.001f), 0.1f);
        float e = fminf(fmaxf(fmaxf(se + eb[0], 0.0f), 0.005f), 0.1f);
        float g = fminf(fmaxf(fmaxf(sg + gb[0], 0.0f), 0.5f),   2.0f);
        out3[row] = a;
        out4[row] = k * 1000.0f;
        out5[row] = e;
        out6[row] = g;
        wsp[row]          = k;
        wsp[512 + row]    = a;
        wsp[1024 + row]   = e;
        wsp[1536 + row]   = g;
    }
}

// -------- fused: truncated-Gaussian FIR + finite diffs + physics + outputs ---
__global__ __launch_bounds__(CBLK) void pc_fused_kernel(
    const float* __restrict__ v,
    const float* __restrict__ wsp,
    const int* __restrict__ use_cond,
    float* __restrict__ out0, float* __restrict__ out1,
    float* __restrict__ out2, float* __restrict__ out7,
    float* __restrict__ dvl,  float* __restrict__ dvr,
    float* __restrict__ out10,
    WTable wt)
{
    __shared__ __align__(16) float win[WIN];
    __shared__ float eL[CBLK], eR[CBLK];

    const int row = blockIdx.y;
    const int i0 = blockIdx.x * CHUNK;
    const int tid = threadIdx.x;
    const float* vrow = v + (long)row * SLEN;

    // stage window [i0-176, i0-176+2400), zero-padded, plain layout, float4
    const int st = i0 - HALO_L;
    for (int g4 = tid; g4 < WIN / 4; g4 += CBLK) {
        const int gw0 = st + 4 * g4;
        float4 val;
        if (gw0 >= 0 && gw0 + 3 < SLEN) {
            val = *(const float4*)(vrow + gw0);
        } else {
            val.x = (gw0 >= 0     && gw0     < SLEN) ? vrow[gw0]     : 0.0f;
            val.y = (gw0 + 1 >= 0 && gw0 + 1 < SLEN) ? vrow[gw0 + 1] : 0.0f;
            val.z = (gw0 + 2 >= 0 && gw0 + 2 < SLEN) ? vrow[gw0 + 2] : 0.0f;
            val.w = (gw0 + 3 >= 0 && gw0 + 3 < SLEN) ? vrow[gw0 + 3] : 0.0f;
        }
        *(float4*)(win + 4 * g4) = val;
    }
    __syncthreads();

    // block-edge v_s values: 64-lane strided partial dot + shfl butterfly.
    // weights recomputed via __expf (kernarg table must not be lane-indexed!)
    const int wv = tid >> 6;
    float edge = 0.0f;
    if (wv == 0 || wv == 3) {
        const int l = tid & 63;
        const int xb = (wv == 0) ? 15 : 2064;   // v_s[i0-1] / v_s[i0+2048]
        float p = 0.0f;
#pragma unroll
        for (int r = 0; r < 6; ++r) {
            const int j = l + (r << 6);
            if (j < TAPS) {
                const float d = (float)(j - RAD);
                p += __expf(d * d * (-1.0f / 1800.0f)) * win[xb + j];
            }
        }
#pragma unroll
        for (int m = 1; m < 64; m <<= 1) p += __shfl_xor(p, m, 64);
        edge = p * (float)(1.0 / 75.19884823893001);
    }

    // FIR: thread outputs i = i0 + 8*tid + t ; window word = 8*tid + 16 + j + t
    float acc[TPO];
#pragma unroll
    for (int t = 0; t < TPO; ++t) acc[t] = 0.0f;

    const float* wp = win + 8 * tid + 16;
    float sreg[16];
    *(float4*)(&sreg[0])  = *(const float4*)(wp);
    *(float4*)(&sreg[4])  = *(const float4*)(wp + 4);
    *(float4*)(&sreg[8])  = *(const float4*)(wp + 8);
    *(float4*)(&sreg[12]) = *(const float4*)(wp + 12);

#pragma unroll
    for (int m = 0; m < 40; ++m) {
        const float4 n0 = *(const float4*)(wp + 8 * m + 16);
        const float4 n1 = *(const float4*)(wp + 8 * m + 20);
#pragma unroll
        for (int c = 0; c < 8; ++c) {
            const float wc = wt.w[8 * m + c];      // constant index -> s_load
#pragma unroll
            for (int t = 0; t < TPO; ++t) acc[t] += wc * sreg[c + t];
        }
#pragma unroll
        for (int k = 0; k < 8; ++k) sreg[k] = sreg[k + 8];
        sreg[8]  = n0.x; sreg[9]  = n0.y; sreg[10] = n0.z; sreg[11] = n0.w;
        sreg[12] = n1.x; sreg[13] = n1.y; sreg[14] = n1.z; sreg[15] = n1.w;
    }
    {   // final tap j = 320
        const float wc = wt.w[320];
#pragma unroll
        for (int t = 0; t < TPO; ++t) acc[t] += wc * sreg[t];
    }

    eL[tid] = acc[0];
    eR[tid] = acc[7];
    __syncthreads();
    const float eRp = (tid > 0)        ? eR[tid - 1] : edge;   // wave 0's edge
    const float eLn = (tid < CBLK - 1) ? eL[tid + 1] : edge;   // wave 3's edge

    const int i8 = i0 + 8 * tid;
    if (i8 < SLEN) {   // grid covers 8192 > 8000: last block's tail threads do
                       // NOTHING (their stores would clobber the next row).
                       // Within the guard 8|8000 -> thread fully in-range.
        // physics epilogue
        const float kk = wsp[row];
        const float aa = wsp[512 + row];
        const float ee = wsp[1024 + row];
        const float gg = wsp[1536 + row];
        const int uc = *use_cond;

        constexpr float DT = 1.6f / 7999.0f;
        constexpr float C1 = 1.0f / (2.0f * DT);
        constexpr float C2 = 1.0f / (DT * DT);

        float dvt8[TPO], dv28[TPO], lg8[TPO];
#pragma unroll
        for (int t = 0; t < TPO; ++t) {
            const int i = i8 + t;
            const float vc = acc[t];
            float vm = (t == 0) ? eRp : acc[t - 1];
            float vp = (t == TPO - 1) ? eLn : acc[t + 1];
            if (i == 0) vm = 0.0f;
            if (i == SLEN - 1) vp = 0.0f;

            const float dv_t = (vp - vm) * C1;
            const float dv2  = (vp + vm - 2.0f * vc) * C2;

            float vn = (vc == 0.0f) ? 0.001f : vc;
            float inv_v = 1.0f / vn;
            if (inv_v != inv_v) inv_v = 0.0f;

            const float term_l1 = vc * kk * dv_t * (1.0f - 2.0f * vc + aa);
            const float term_l2 = inv_v * dv_t * dv_t;
            const float term_lt = 1000.0f * term_l1 + term_l2 - dv2;
            const float term_r1 = vc * (vc - gg * kk * 1000.0f * (1.0f - vc) * (vc - aa));
            const float term_rt = ee * (term_r1 + gg * dv_t);
            float dvo = term_lt - term_rt;
            if (uc) {
                if (vrow[i] <= 0.0f) dvo = 0.0f;
            }
            dvt8[t] = dv_t;
            dv28[t] = dv2;
            lg8[t]  = __logf(dvo * dvo + 1e-5f);
        }

        const long rs = (long)row * SLEN + i8;
        *(float4*)(out1 + rs)     = make_float4(dvt8[0], dvt8[1], dvt8[2], dvt8[3]);
        *(float4*)(out1 + rs + 4) = make_float4(dvt8[4], dvt8[5], dvt8[6], dvt8[7]);
        *(float4*)(out2 + rs)     = make_float4(dv28[0], dv28[1], dv28[2], dv28[3]);
        *(float4*)(out2 + rs + 4) = make_float4(dv28[4], dv28[5], dv28[6], dv28[7]);
        const float4 c16 = make_float4(1.6f, 1.6f, 1.6f, 1.6f);
        *(float4*)(out7 + rs)      = c16;
        *(float4*)(out7 + rs + 4)  = c16;
        *(float4*)(out10 + rs)     = c16;
        *(float4*)(out10 + rs + 4) = c16;

        const long rb = (long)row * (SLEN + 1) + i8;
        f4u a0 = {acc[0], acc[1], acc[2], acc[3]};
        f4u a1 = {acc[4], acc[5], acc[6], acc[7]};
        *(f4u*)(dvr + rb)     = a0;          // dv_r[i] = v_s[i]
        *(f4u*)(dvr + rb + 4) = a1;
        *(f4u*)(dvl + rb + 1) = a0;          // dv_l[i+1] = v_s[i]
        *(f4u*)(dvl + rb + 5) = a1;
        if (i8 == 0)        dvl[(long)row * (SLEN + 1)] = 0.0f;
        if (i8 == SLEN - 8) dvr[(long)row * (SLEN + 1) + SLEN] = 0.0f;

        const long r0 = (long)row * 7700;
        if (i8 >= 100 && i8 + 8 <= 950) {
            *(float4*)(out0 + r0 + i8 - 100) = make_float4(lg8[0], lg8[1], lg8[2], lg8[3]);
            *(float4*)(out0 + r0 + i8 - 96)  = make_float4(lg8[4], lg8[5], lg8[6], lg8[7]);
        } else if (i8 >= 1050 && i8 + 8 <= 7900) {
            *(float4*)(out0 + r0 + i8 - 200) = make_float4(lg8[0], lg8[1], lg8[2], lg8[3]);
            *(float4*)(out0 + r0 + i8 - 196) = make_float4(lg8[4], lg8[5], lg8[6], lg8[7]);
        } else {
#pragma unroll
            for (int t = 0; t < TPO; ++t) {
                const int i = i8 + t;
                if (i >= 100 && i < 950)        out0[r0 + (i - 100)] = lg8[t];
                else if (i >= 1050 && i < 7900) out0[r0 + (i - 200)] = lg8[t];
            }
        }
    }
}

static void build_wtable(WTable* wt) {
    // reference: k = exp(-x^2/(2*30^2)) over x=-3500..3500, normalized by full sum
    double norm = 0.0;
    for (int d = -3500; d <= 3500; ++d)
        norm += exp(-(double)d * (double)d / 1800.0);
    for (int j = 0; j < TAPS; ++j) {
        const int d = j - RAD;
        wt->w[j] = (float)(exp(-(double)d * (double)d / 1800.0) / norm);
    }
}

extern "C" void kernel_launch(void* const* d_in, const int* in_sizes, int n_in,
                              void* d_out, int out_size, void* d_ws, size_t ws_size,
                              hipStream_t stream)
{
    const float* v_out = (const float*)d_in[0];
    const float* b  = (const float*)d_in[1];
    const float* kw = (const float*)d_in[2];
    const float* kb = (const float*)d_in[3];
    const float* aw = (const float*)d_in[4];
    const float* ab = (const float*)d_in[5];
    const float* ew = (const float*)d_in[6];
    const float* eb = (const float*)d_in[7];
    const float* gw = (const float*)d_in[8];
    const float* gb = (const float*)d_in[9];
    const int* use_cond = (const int*)d_in[10];
    float* out = (float*)d_out;
    float* wsp = (float*)d_ws;   // 2048 floats: k,a,eps,gamma per row

    WTable wt;
    build_wtable(&wt);

    pc_params_kernel<<<NBATCH, 64, 0, stream>>>(
        b, kw, kb, aw, ab, ew, eb, gw, gb,
        out + O3, out + O4, out + O5, out + O6, wsp);

    pc_fused_kernel<<<dim3(SLEN / CHUNK + ((SLEN % CHUNK) ? 1 : 0), NBATCH), CBLK, 0, stream>>>(
        v_out, wsp, use_cond,
        out + O0, out + O1, out + O2, out + O7,
        out + O8, out + O9, out + O10, wt);
}

// Round 5
// 207.277 us; speedup vs baseline: 2.4841x; 2.4841x over previous
//
#include <hip/hip_runtime.h>
#include <math.h>

#define SLEN 8000
#define NBATCH 512
#define DDIM 256

// ---- fused conv+pointwise config ----
#define RAD 160
#define TAPS 321                 // truncated Gaussian: tail mass ~1e-7
#define CHUNK 2048
#define CBLK 128                 // 2 waves
#define TPO 16                   // outputs per thread
#define HALO_L 176               // 16 extra left so v_s[i0-1] is computable
#define WIN 2400                 // 176 + 2048 + 160 + 16 slack (exactly fits prefetch)
#define LDSZ 2700                // phi(2399)=2698; phi(x)=x+(x>>3), stride-18 lanes: 2-way=free

// output element offsets (flat concat in reference return order)
#define O0  0            // dv_out sliced  512*7700
#define O1  3942400      // dv_t           512*8000
#define O2  8038400      // dv2_t          512*8000
#define O3  12134400     // a              512
#define O4  12134912     // k*1000         512
#define O5  12135424     // epsilon        512
#define O6  12135936     // gamma          512
#define O7  12136448     // t_             512*8000
#define O8  16232448     // dv_l           512*8001
#define O9  20328960     // dv_r           512*8001
#define O10 24425472     // t_out          512*8000

#define WS_WTAB 2048     // weight table lives at wsp + 2048 (321 floats)

// unaligned-capable 16B vector (dv_l/dv_r rows are 8001 floats -> 4B aligned)
typedef float f4u __attribute__((vector_size(16), aligned(4)));

// ---------------- weight table: double-precision Gaussian taps ---------------
__global__ __launch_bounds__(384) void pc_wtab_kernel(float* __restrict__ wtab) {
    const int j = threadIdx.x;
    if (j < TAPS) {
        const double d = (double)(j - RAD);
        // norm = sum_{-3500..3500} exp(-d^2/1800) = sigma*sqrt(2pi) to ~1e-16
        wtab[j] = (float)(exp(-d * d / 1800.0) * (1.0 / 75.1988482389300059));
    }
}

// ---------------- params: one wave per row, shfl butterfly reduction ---------
__global__ __launch_bounds__(64) void pc_params_kernel(
    const float* __restrict__ b,
    const float* __restrict__ kw, const float* __restrict__ kb,
    const float* __restrict__ aw, const float* __restrict__ ab,
    const float* __restrict__ ew, const float* __restrict__ eb,
    const float* __restrict__ gw, const float* __restrict__ gb,
    float* __restrict__ out3, float* __restrict__ out4,
    float* __restrict__ out5, float* __restrict__ out6,
    float* __restrict__ wsp)
{
    const int row = blockIdx.x;
    const int l = threadIdx.x;
    const float4 bb = *(const float4*)(b + (long)row * DDIM + 4 * l);
    const float4 k4 = *(const float4*)(kw + 4 * l);
    const float4 a4 = *(const float4*)(aw + 4 * l);
    const float4 e4 = *(const float4*)(ew + 4 * l);
    const float4 g4 = *(const float4*)(gw + 4 * l);
    float sk = bb.x * k4.x + bb.y * k4.y + bb.z * k4.z + bb.w * k4.w;
    float sa = bb.x * a4.x + bb.y * a4.y + bb.z * a4.z + bb.w * a4.w;
    float se = bb.x * e4.x + bb.y * e4.y + bb.z * e4.z + bb.w * e4.w;
    float sg = bb.x * g4.x + bb.y * g4.y + bb.z * g4.z + bb.w * g4.w;
#pragma unroll
    for (int m = 1; m < 64; m <<= 1) {
        sk += __shfl_xor(sk, m, 64);
        sa += __shfl_xor(sa, m, 64);
        se += __shfl_xor(se, m, 64);
        sg += __shfl_xor(sg, m, 64);
    }
    if (l == 0) {
        float k = fminf(fmaxf(fmaxf(sk + kb[0], 0.0f), 0.1f),   1.0f);
        float a = fminf(fmaxf(fmaxf(sa + ab[0], 0.0f), 0.001f), 0.1f);
        float e = fminf(fmaxf(fmaxf(se + eb[0], 0.0f), 0.005f), 0.1f);
        float g = fminf(fmaxf(fmaxf(sg + gb[0], 0.0f), 0.5f),   2.0f);
        out3[row] = a;
        out4[row] = k * 1000.0f;
        out5[row] = e;
        out6[row] = g;
        wsp[row]          = k;
        wsp[512 + row]    = a;
        wsp[1024 + row]   = e;
        wsp[1536 + row]   = g;
    }
}

// -------- fused: truncated-Gaussian FIR + finite diffs + physics + outputs ---
__global__ __launch_bounds__(CBLK) void pc_fused_kernel(
    const float* __restrict__ v,
    const float* __restrict__ wsp,
    const float* __restrict__ wtab,
    const int* __restrict__ use_cond,
    float* __restrict__ out0, float* __restrict__ out1,
    float* __restrict__ out2, float* __restrict__ out7,
    float* __restrict__ dvl,  float* __restrict__ dvr,
    float* __restrict__ out10)
{
    __shared__ float lds[LDSZ];
    __shared__ float eL[CBLK], eR[CBLK];

    const int row = blockIdx.y;
    const int i0 = blockIdx.x * CHUNK;
    const int tid = threadIdx.x;
    const float* vrow = v + (long)row * SLEN;

    // stage window [i0-176, i0-176+2400), zero-padded, swizzled phi(x)=x+(x>>3)
    // (aligned float4 stays contiguous under phi: phi(4q+k)=phi(4q)+k)
    const int st = i0 - HALO_L;
    for (int q = tid; q < WIN / 4; q += CBLK) {
        const int g0 = st + 4 * q;
        float4 val;
        if (g0 >= 0 && g0 + 3 < SLEN) {
            val = *(const float4*)(vrow + g0);
        } else {
            val.x = (g0 >= 0     && g0     < SLEN) ? vrow[g0]     : 0.0f;
            val.y = (g0 + 1 >= 0 && g0 + 1 < SLEN) ? vrow[g0 + 1] : 0.0f;
            val.z = (g0 + 2 >= 0 && g0 + 2 < SLEN) ? vrow[g0 + 2] : 0.0f;
            val.w = (g0 + 3 >= 0 && g0 + 3 < SLEN) ? vrow[g0 + 3] : 0.0f;
        }
        const int p = 4 * q + ((4 * q) >> 3);
        lds[p] = val.x; lds[p + 1] = val.y; lds[p + 2] = val.z; lds[p + 3] = val.w;
    }
    __syncthreads();

    // block-edge v_s: wave0 -> v_s[i0-1], wave1 -> v_s[i0+2048].
    // 64-lane strided partial dot (weights via __expf; err ~1e-6, x2.5e7 amp
    // ~25 abs -- fine) + shfl butterfly.
    float edge;
    {
        const int l = tid & 63;
        const int xb = (tid < 64) ? 15 : 2064;
        float p = 0.0f;
#pragma unroll
        for (int r = 0; r < 6; ++r) {
            const int j = l + (r << 6);
            if (j < TAPS) {
                const float d = (float)(j - RAD);
                const int x = xb + j;
                p += __expf(d * d * (-1.0f / 1800.0f)) * lds[x + (x >> 3)];
            }
        }
#pragma unroll
        for (int m = 1; m < 64; m <<= 1) p += __shfl_xor(p, m, 64);
        edge = p * (float)(1.0 / 75.1988482389300059);
    }

    // FIR: thread outputs i = i0 + 16*tid + c (c=0..15); window x = 16*tid+16+j+c.
    // 8-groups are contiguous under phi: group a at lds + 9*a. Base group
    // a0 = 2*tid+2; block M (taps 16M..16M+15) uses groups a0+2M .. a0+2M+3.
    float acc[TPO];
#pragma unroll
    for (int t = 0; t < TPO; ++t) acc[t] = 0.0f;

    const float* pg = lds + 18 * tid + 18;   // group a0
    float sreg[32];
#pragma unroll
    for (int k = 0; k < 8; ++k) {
        sreg[k]      = pg[k];
        sreg[8 + k]  = pg[9 + k];
        sreg[16 + k] = pg[18 + k];
        sreg[24 + k] = pg[27 + k];
    }

#pragma unroll 2
    for (int M = 0; M < 20; ++M) {
        // wave-uniform weight loads (const __restrict__ -> scalar/L1 path)
        const float4 wA = *(const float4*)(wtab + 16 * M);
        const float4 wB = *(const float4*)(wtab + 16 * M + 4);
        const float4 wC = *(const float4*)(wtab + 16 * M + 8);
        const float4 wD = *(const float4*)(wtab + 16 * M + 12);
        const float wc[16] = {wA.x, wA.y, wA.z, wA.w, wB.x, wB.y, wB.z, wB.w,
                              wC.x, wC.y, wC.z, wC.w, wD.x, wD.y, wD.z, wD.w};
        // prefetch next 2 groups (M=19 reads up to phi-idx 2698 -- in bounds)
        float nf[16];
        const float* pn = pg + 9 * (4 + 2 * M);
#pragma unroll
        for (int k = 0; k < 8; ++k) { nf[k] = pn[k]; nf[8 + k] = pn[9 + k]; }
#pragma unroll
        for (int c = 0; c < 16; ++c) {
#pragma unroll
            for (int t = 0; t < TPO; ++t) acc[t] += wc[c] * sreg[c + t];
        }
#pragma unroll
        for (int k = 0; k < 16; ++k) sreg[k] = sreg[k + 16];
#pragma unroll
        for (int k = 0; k < 16; ++k) sreg[16 + k] = nf[k];
    }
    {   // final tap j = 320: x = 16*tid + 336 + t -> sreg[16 + t]
        const float w320 = wtab[320];
#pragma unroll
        for (int t = 0; t < TPO; ++t) acc[t] += w320 * sreg[16 + t];
    }

    eL[tid] = acc[0];
    eR[tid] = acc[15];
    __syncthreads();

    const int i8 = i0 + 16 * tid;
    if (i8 < SLEN) {   // grid covers 8192 > 8000: tail threads of the last
                       // block must do NOTHING (stores would clobber next row).
                       // Within the guard 16 | 8000 -> thread fully in-range.
        const float vprev = (tid > 0)        ? eR[tid - 1] : edge;  // wave0 edge
        const float vnext = (tid < CBLK - 1) ? eL[tid + 1] : edge;  // wave1 edge

        const float kk = wsp[row];
        const float aa = wsp[512 + row];
        const float ee = wsp[1024 + row];
        const float gg = wsp[1536 + row];
        const int uc = *use_cond;

        constexpr float DT = 1.6f / 7999.0f;
        constexpr float C1 = 1.0f / (2.0f * DT);
        constexpr float C2 = 1.0f / (DT * DT);

        const long rs = (long)row * SLEN + i8;
        const long rb = (long)row * (SLEN + 1) + i8;
        const long r0 = (long)row * 7700;
        const float4 c16 = make_float4(1.6f, 1.6f, 1.6f, 1.6f);

        // process in chunks of 8 to keep live ranges small (no spill)
#pragma unroll
        for (int h = 0; h < 2; ++h) {
            float dvt8[8], dv28[8], lg8[8];
#pragma unroll
            for (int u = 0; u < 8; ++u) {
                const int c = 8 * h + u;
                const int i = i8 + c;
                const float vc = acc[c];
                float vm = (c == 0)  ? vprev : acc[c - 1];
                float vp = (c == 15) ? vnext : acc[c + 1];
                if (i == 0) vm = 0.0f;
                if (i == SLEN - 1) vp = 0.0f;

                const float dv_t = (vp - vm) * C1;
                const float dv2  = (vp + vm - 2.0f * vc) * C2;

                float vn = (vc == 0.0f) ? 0.001f : vc;
                float inv_v = 1.0f / vn;
                if (inv_v != inv_v) inv_v = 0.0f;

                const float term_l1 = vc * kk * dv_t * (1.0f - 2.0f * vc + aa);
                const float term_l2 = inv_v * dv_t * dv_t;
                const float term_lt = 1000.0f * term_l1 + term_l2 - dv2;
                const float term_r1 = vc * (vc - gg * kk * 1000.0f * (1.0f - vc) * (vc - aa));
                const float term_rt = ee * (term_r1 + gg * dv_t);
                float dvo = term_lt - term_rt;
                if (uc) {
                    if (vrow[i] <= 0.0f) dvo = 0.0f;
                }
                dvt8[u] = dv_t;
                dv28[u] = dv2;
                lg8[u]  = __logf(dvo * dvo + 1e-5f);
            }

            const int ib = i8 + 8 * h;       // 8-aligned
            const long rsh = rs + 8 * h;
            *(float4*)(out1 + rsh)     = make_float4(dvt8[0], dvt8[1], dvt8[2], dvt8[3]);
            *(float4*)(out1 + rsh + 4) = make_float4(dvt8[4], dvt8[5], dvt8[6], dvt8[7]);
            *(float4*)(out2 + rsh)     = make_float4(dv28[0], dv28[1], dv28[2], dv28[3]);
            *(float4*)(out2 + rsh + 4) = make_float4(dv28[4], dv28[5], dv28[6], dv28[7]);
            *(float4*)(out7 + rsh)      = c16;
            *(float4*)(out7 + rsh + 4)  = c16;
            *(float4*)(out10 + rsh)     = c16;
            *(float4*)(out10 + rsh + 4) = c16;

            const long rbh = rb + 8 * h;
            f4u a0 = {acc[8 * h],     acc[8 * h + 1], acc[8 * h + 2], acc[8 * h + 3]};
            f4u a1 = {acc[8 * h + 4], acc[8 * h + 5], acc[8 * h + 6], acc[8 * h + 7]};
            *(f4u*)(dvr + rbh)     = a0;     // dv_r[i] = v_s[i]
            *(f4u*)(dvr + rbh + 4) = a1;
            *(f4u*)(dvl + rbh + 1) = a0;     // dv_l[i+1] = v_s[i]
            *(f4u*)(dvl + rbh + 5) = a1;

            if (ib >= 100 && ib + 8 <= 950) {
                *(float4*)(out0 + r0 + ib - 100) = make_float4(lg8[0], lg8[1], lg8[2], lg8[3]);
                *(float4*)(out0 + r0 + ib - 96)  = make_float4(lg8[4], lg8[5], lg8[6], lg8[7]);
            } else if (ib >= 1050 && ib + 8 <= 7900) {
                *(float4*)(out0 + r0 + ib - 200) = make_float4(lg8[0], lg8[1], lg8[2], lg8[3]);
                *(float4*)(out0 + r0 + ib - 196) = make_float4(lg8[4], lg8[5], lg8[6], lg8[7]);
            } else {
#pragma unroll
                for (int u = 0; u < 8; ++u) {
                    const int i = ib + u;
                    if (i >= 100 && i < 950)        out0[r0 + (i - 100)] = lg8[u];
                    else if (i >= 1050 && i < 7900) out0[r0 + (i - 200)] = lg8[u];
                }
            }
        }
        if (i8 == 0)           dvl[(long)row * (SLEN + 1)] = 0.0f;
        if (i8 == SLEN - TPO)  dvr[(long)row * (SLEN + 1) + SLEN] = 0.0f;
    }
}

extern "C" void kernel_launch(void* const* d_in, const int* in_sizes, int n_in,
                              void* d_out, int out_size, void* d_ws, size_t ws_size,
                              hipStream_t stream)
{
    const float* v_out = (const float*)d_in[0];
    const float* b  = (const float*)d_in[1];
    const float* kw = (const float*)d_in[2];
    const float* kb = (const float*)d_in[3];
    const float* aw = (const float*)d_in[4];
    const float* ab = (const float*)d_in[5];
    const float* ew = (const float*)d_in[6];
    const float* eb = (const float*)d_in[7];
    const float* gw = (const float*)d_in[8];
    const float* gb = (const float*)d_in[9];
    const int* use_cond = (const int*)d_in[10];
    float* out = (float*)d_out;
    float* wsp = (float*)d_ws;   // [0,2048): k,a,eps,gamma; [2048,2369): wtab

    pc_wtab_kernel<<<1, 384, 0, stream>>>(wsp + WS_WTAB);

    pc_params_kernel<<<NBATCH, 64, 0, stream>>>(
        b, kw, kb, aw, ab, ew, eb, gw, gb,
        out + O3, out + O4, out + O5, out + O6, wsp);

    pc_fused_kernel<<<dim3((SLEN + CHUNK - 1) / CHUNK, NBATCH), CBLK, 0, stream>>>(
        v_out, wsp, wsp + WS_WTAB, use_cond,
        out + O0, out + O1, out + O2, out + O7,
        out + O8, out + O9, out + O10);
}